// Round 18
// baseline (225.038 us; speedup 1.0000x reference)
//
#include <hip/hip_runtime.h>
#include <hip/hip_bf16.h>
#include <stdint.h>

typedef __attribute__((ext_vector_type(8))) short short8;
typedef __attribute__((ext_vector_type(4))) float f32x4;
typedef unsigned short u16;

#define EMBED 1024
#define SEQ 2048
#define NBATCH 4
#define MROWS (NBATCH * SEQ) /* 8192 */

__device__ __forceinline__ u16 f2bf(float f) {
  union { float f; uint32_t u; } v; v.f = f;
  uint32_t r = v.u + 0x7fffu + ((v.u >> 16) & 1u);
  return (u16)(r >> 16);
}

__device__ __forceinline__ uint32_t cvtpk(float lo, float hi) {
  uint32_t r;
  asm("v_cvt_pk_bf16_f32 %0, %1, %2" : "=v"(r) : "v"(lo), "v"(hi));
  return r;
}

// raw HW 2^x
__device__ __forceinline__ float vexp2(float x) {
  float r;
  asm("v_exp_f32 %0, %1" : "=v"(r) : "v"(x));
  return r;
}

__device__ __forceinline__ void gld16(const void* g, void* l) {
  __builtin_amdgcn_global_load_lds((const __attribute__((address_space(1))) void*)g,
                                   (__attribute__((address_space(3))) void*)l, 16, 0, 0);
}

// ---------------- prep: 4 weight transposes fp32[k][n] -> bf16[n][k] ----------------
__global__ __launch_bounds__(256) void prep_kernel(const float* __restrict__ W0,
                                                   const float* __restrict__ W1,
                                                   const float* __restrict__ W2,
                                                   const float* __restrict__ W3,
                                                   u16* __restrict__ T0,
                                                   u16* __restrict__ T1,
                                                   u16* __restrict__ T2,
                                                   u16* __restrict__ T3) {
  int id = blockIdx.x;
  int z = id >> 10;
  const float* W = z == 0 ? W0 : (z == 1 ? W1 : (z == 2 ? W2 : W3));
  u16* Wt = z == 0 ? T0 : (z == 1 ? T1 : (z == 2 ? T2 : T3));
  __shared__ float tile[32][33];
  int bx = (id & 31) * 32, by = ((id >> 5) & 31) * 32;
  int tx = threadIdx.x & 31, ty = threadIdx.x >> 5; // 32 x 8
#pragma unroll
  for (int i = 0; i < 32; i += 8)
    tile[ty + i][tx] = W[(size_t)(by + ty + i) * EMBED + bx + tx];
  __syncthreads();
#pragma unroll
  for (int i = 0; i < 32; i += 8)
    Wt[(size_t)(bx + ty + i) * EMBED + by + tx] = f2bf(tile[tx][ty + i]);
}

// ---------------- QKV GEMM: fused fp32->bf16, counted-vmcnt pipelined ----------------
// XCD co-location (id = x*8 + (p>>3)*64 + (p&7), p=z*64+y). A staged in BK=32 fp32
// tiles, TRIPLE-buffered (rows 128B, unit-XOR row&7 -> 2-way-free reads). B staged in
// BK=64 bf16 tiles (R12-exact layout, 0-conflict), DOUBLE-buffered. Per half-step ht:
// issue A(ht+2) [+ B pair on even ht], compute(ht), then vmcnt(8)/(4) (never 0) +
// barrier -- newest staging group stays in flight across the barrier (T3/T4 recipe).
__global__ __launch_bounds__(256) void qkv_gemm(const float* __restrict__ Aq,
                                                const float* __restrict__ Ak,
                                                const float* __restrict__ Av,
                                                const u16* __restrict__ Wqt,
                                                const u16* __restrict__ Wkt,
                                                const u16* __restrict__ Wvt,
                                                u16* __restrict__ Qb,
                                                u16* __restrict__ Kb,
                                                u16* __restrict__ Vtb,
                                                float qscale) {
  constexpr int K = 1024;
  __shared__ float lsAf[3][128 * 32];  // 3 x 16KB
  __shared__ u16   lsB[2][128 * 64];   // 2 x 16KB

  const int id = blockIdx.x;
  const int xcd = id & 7;
  const int rest = id >> 3;
  const int bx = rest & 7;
  const int p = (rest >> 3) * 8 + xcd;  // [0,192)
  const int z = p >> 6;
  const int by = p & 63;

  const float* A = z == 0 ? Aq : (z == 1 ? Ak : Av);
  const u16* Bt  = z == 0 ? Wqt : (z == 1 ? Wkt : Wvt);
  u16* outp      = z == 0 ? Qb : (z == 1 ? Kb : Vtb);
  const float oscale = z == 0 ? qscale : 1.0f;
  const int epi = (z == 2) ? 1 : 0;

  const int t = threadIdx.x, l = t & 63, w = t >> 6;
  const int g = l >> 4, r15 = l & 15;
  const int m0 = by * 128, n0 = bx * 128;
  const int wm = (w >> 1) * 64, wn = (w & 1) * 64;
  f32x4 acc[4][4] = {};

  // A staging (BK=32 tile, 128B rows of 8x16B units): row = j*32 + (t>>3), u = t&7
  const float* Apf[4];
#pragma unroll
  for (int j = 0; j < 4; ++j) {
    int row = j * 32 + (t >> 3);
    Apf[j] = A + (size_t)(m0 + row) * K + ((t & 7) ^ (row & 7)) * 4;
  }
  // B staging (BK=64 tile, R12-exact): row = j*32 + (t>>3)
  const u16* Bp[4];
#pragma unroll
  for (int j = 0; j < 4; ++j) {
    int row = j * 32 + (t >> 3);
    int colswz = (((t & 7) * 16) ^ ((row & 7) << 4)) >> 1;
    Bp[j] = Bt + (size_t)(n0 + row) * K + colswz;
  }

  auto STAGE_A = [&](int buf, int k0) {  // k0 in elements (multiple of 32)
#pragma unroll
    for (int j = 0; j < 4; ++j)
      gld16(Apf[j] + k0, (char*)&lsAf[buf][0] + j * 4096 + w * 1024);
  };
  auto STAGE_B = [&](int buf, int k0) {  // k0 multiple of 64
#pragma unroll
    for (int j = 0; j < 4; ++j)
      gld16(Bp[j] + k0, (char*)&lsB[buf][0] + j * 4096 + w * 1024);
  };

  auto COMPUTE = [&](int abuf, int bbuf, int kk) {
    short8 af[4], bfv[4];
#pragma unroll
    for (int mi = 0; mi < 4; ++mi) {
      int row = wm + mi * 16 + r15;
      int s = row & 7;
      const char* base = (const char*)&lsAf[abuf][0] + row * 128;
      f32x4 a0 = *(const f32x4*)(base + (((2 * g) ^ s) * 16));
      f32x4 a1 = *(const f32x4*)(base + (((2 * g + 1) ^ s) * 16));
      union { uint32_t u[4]; short8 sv; } pu;
      pu.u[0] = cvtpk(a0[0], a0[1]);
      pu.u[1] = cvtpk(a0[2], a0[3]);
      pu.u[2] = cvtpk(a1[0], a1[1]);
      pu.u[3] = cvtpk(a1[2], a1[3]);
      af[mi] = pu.sv;
    }
#pragma unroll
    for (int ni = 0; ni < 4; ++ni) {
      int row = wn + ni * 16 + r15;
      bfv[ni] = *(const short8*)((const char*)&lsB[bbuf][0] + row * 128 + ((kk * 64 + g * 16) ^ ((row & 7) << 4)));
    }
#pragma unroll
    for (int mi = 0; mi < 4; ++mi)
#pragma unroll
      for (int ni = 0; ni < 4; ++ni)
        acc[mi][ni] = __builtin_amdgcn_mfma_f32_16x16x32_bf16(af[mi], bfv[ni], acc[mi][ni], 0, 0, 0);
  };

  // prologue: A(0), B(pair0), A(1) -- 12 ops, full drain once
  STAGE_A(0, 0);
  STAGE_B(0, 0);
  STAGE_A(1, 32);
  asm volatile("s_waitcnt vmcnt(0) lgkmcnt(0)" ::: "memory");
  __builtin_amdgcn_s_barrier();
  __builtin_amdgcn_sched_barrier(0);

  int aC = 0, aP = 1, aQ = 2;  // abuf for ht, ht+1, ht+2 (rotates per pair)
  int bC = 0;                  // bbuf for current pair

#pragma unroll 1
  for (int hp = 0; hp < 15; ++hp) {
    // even half: ht = 2hp
    STAGE_A(aQ, (2 * hp + 2) * 32);
    STAGE_B(bC ^ 1, (hp + 1) * 64);
    COMPUTE(aC, bC, 0);
    asm volatile("s_waitcnt vmcnt(8)" ::: "memory");   // keep 8-group in flight
    asm volatile("s_waitcnt lgkmcnt(0)" ::: "memory");
    __builtin_amdgcn_s_barrier();
    __builtin_amdgcn_sched_barrier(0);
    // odd half: ht = 2hp+1
    STAGE_A(aC, (2 * hp + 3) * 32);                    // aC free: read finished pre-barrier
    COMPUTE(aP, bC, 1);
    asm volatile("s_waitcnt vmcnt(4)" ::: "memory");   // retire 8-group, keep new A
    asm volatile("s_waitcnt lgkmcnt(0)" ::: "memory");
    __builtin_amdgcn_s_barrier();
    __builtin_amdgcn_sched_barrier(0);
    // rotate: (aC,aP,aQ) <- (aQ,aC,aP) ; bC flips
    int tmp = aQ; aQ = aP; aP = aC; aC = tmp;
    bC ^= 1;
  }

  // tail: ht = 30, 31 (aC=0, aP=1, bC=1 by invariant)
  COMPUTE(aC, bC, 0);
  asm volatile("s_waitcnt vmcnt(0) lgkmcnt(0)" ::: "memory");
  __builtin_amdgcn_s_barrier();
  __builtin_amdgcn_sched_barrier(0);
  COMPUTE(aP, bC, 1);

#pragma unroll
  for (int mi = 0; mi < 4; ++mi)
#pragma unroll
    for (int ni = 0; ni < 4; ++ni)
#pragma unroll
      for (int r = 0; r < 4; ++r) {
        int row = m0 + wm + mi * 16 + g * 4 + r;   // D: row=(l>>4)*4+reg
        int col = n0 + wn + ni * 16 + r15;         //    col=l&15
        float v = acc[mi][ni][r];
        if (epi == 0) {
          ((u16*)outp)[(((size_t)(row >> 11) * 16 + (col >> 6)) * SEQ + (row & 2047)) * 64 + (col & 63)] = f2bf(v * oscale);
        } else {
          ((u16*)outp)[(((size_t)(row >> 11) * 16 + (col >> 6)) * 64 + (col & 63)) * SEQ + (row & 2047)] = f2bf(v);
        }
      }
}

// ---------------- final projection: C = A_bf16 * Wot^T, fp32 out + bias ----------------
__global__ __launch_bounds__(256) void gemm_o(const u16* __restrict__ A,
                                              const u16* __restrict__ Bt,
                                              float* __restrict__ outp,
                                              const float* __restrict__ bias) {
  constexpr int K = 1024;
  __shared__ u16 lsA[128 * 64];
  __shared__ u16 lsB[128 * 64];

  const int id = blockIdx.x;
  const int xcd = id & 7;
  const int rest = id >> 3;
  const int bx = rest & 7;
  const int by = (rest >> 3) * 8 + xcd;  // [0,64)

  const int t = threadIdx.x, l = t & 63, w = t >> 6;
  const int g = l >> 4, r15 = l & 15;
  const int m0 = by * 128, n0 = bx * 128;
  const int wm = (w >> 1) * 64, wn = (w & 1) * 64;
  f32x4 acc[4][4] = {};
  const int srow = t >> 3;
  const int sc16 = (t & 7) * 16;

  const u16* Ap[4]; const u16* Bp[4];
#pragma unroll
  for (int j = 0; j < 4; ++j) {
    int row = srow + j * 32;
    int colswz = (sc16 ^ ((row & 7) << 4)) >> 1;
    Ap[j] = A  + (size_t)(m0 + row) * K + colswz;
    Bp[j] = Bt + (size_t)(n0 + row) * K + colswz;
  }

  for (int k0 = 0; k0 < K; k0 += 64) {
#pragma unroll
    for (int j = 0; j < 4; ++j) {
      gld16(Ap[j] + k0, lsA + j * 2048 + w * 512);
      gld16(Bp[j] + k0, lsB + j * 2048 + w * 512);
    }
    __syncthreads();
    short8 af[2][4], bfv[2][4];
#pragma unroll
    for (int kk = 0; kk < 2; ++kk) {
#pragma unroll
      for (int mi = 0; mi < 4; ++mi) {
        int row = wm + mi * 16 + r15;
        af[kk][mi] = *(const short8*)((const char*)lsA + row * 128 + ((kk * 64 + g * 16) ^ ((row & 7) << 4)));
      }
#pragma unroll
      for (int ni = 0; ni < 4; ++ni) {
        int row = wn + ni * 16 + r15;
        bfv[kk][ni] = *(const short8*)((const char*)lsB + row * 128 + ((kk * 64 + g * 16) ^ ((row & 7) << 4)));
      }
    }
#pragma unroll
    for (int kk = 0; kk < 2; ++kk)
#pragma unroll
      for (int mi = 0; mi < 4; ++mi)
#pragma unroll
        for (int ni = 0; ni < 4; ++ni)
          acc[mi][ni] = __builtin_amdgcn_mfma_f32_16x16x32_bf16(af[kk][mi], bfv[kk][ni], acc[mi][ni], 0, 0, 0);
    __syncthreads();
  }

#pragma unroll
  for (int mi = 0; mi < 4; ++mi)
#pragma unroll
    for (int ni = 0; ni < 4; ++ni)
#pragma unroll
      for (int r = 0; r < 4; ++r) {
        int row = m0 + wm + mi * 16 + g * 4 + r;
        int col = n0 + wn + ni * 16 + r15;
        outp[(size_t)row * EMBED + col] = acc[mi][ni][r] + bias[col];
      }
}

// ---------------- flash attention: 3-deep counted-vmcnt pipeline (R12-exact) ----------------
__global__ __launch_bounds__(256) void attn_kernel(const u16* __restrict__ Q,
                                                   const u16* __restrict__ Kb,
                                                   const u16* __restrict__ Vt,
                                                   u16* __restrict__ AO) {
  __shared__ u16 lsK[3][64 * 64];
  __shared__ u16 lsV[2][64 * 64];
  const int t = threadIdx.x, l = t & 63, w = t >> 6;
  const int g = l >> 4, r15 = l & 15;

  const int flat = blockIdx.x;
  const int work = (flat & 7) * 128 + (flat >> 3);
  const int bh = work >> 4;
  const int q0 = (work & 15) * 128;

  const u16* Qh = Q + (size_t)bh * SEQ * 64;
  const u16* Kh = Kb + (size_t)bh * SEQ * 64;
  const u16* Vh = Vt + (size_t)bh * 64 * SEQ;

  short8 qf[2][2];
#pragma unroll
  for (int qi = 0; qi < 2; ++qi)
#pragma unroll
    for (int dh = 0; dh < 2; ++dh)
      qf[qi][dh] = *(const short8*)&Qh[(size_t)(q0 + w * 32 + qi * 16 + r15) * 64 + dh * 32 + g * 8];

  const short8 kones = { 0x3F80, 0x3F80, 0x3F80, 0x3F80, 0x3F80, 0x3F80, 0x3F80, 0x3F80 };
  f32x4 ssum[2] = {};
  f32x4 oacc[4][2] = {};

  const int srow = t >> 3;         // 0..31
  const int scolb = (t & 7) * 16;  // byte col within 128B row

  uint4 vreg[2][2];  // [tile parity][j]

  auto STAGE_K = [&](int buf, int kv0) {
#pragma unroll
    for (int j = 0; j < 2; ++j) {
      int row = j * 32 + srow;
      int colswz = (scolb ^ ((row & 7) << 4)) >> 1;
      gld16(Kh + (size_t)(kv0 + row) * 64 + colswz, &lsK[buf][j * 2048 + w * 512]);
    }
  };
  auto VLOAD = [&](int par, int kv0) {
#pragma unroll
    for (int j = 0; j < 2; ++j) {
      int row = j * 32 + srow;  // d-row of V^T
      vreg[par][j] = *(const uint4*)(Vh + (size_t)row * SEQ + kv0 + (scolb >> 1));
    }
  };
  auto VSTORE = [&](int buf, int par) {
#pragma unroll
    for (int j = 0; j < 2; ++j) {
      int row = j * 32 + srow;
      int c4 = (row & 7) << 4, c3 = ((row >> 3) & 1) << 3;
      char* base = (char*)&lsV[buf][0] + row * 128 + (scolb ^ c4);
      *(uint2*)(base + c3)       = make_uint2(vreg[par][j].x, vreg[par][j].y);
      *(uint2*)(base + (8 ^ c3)) = make_uint2(vreg[par][j].z, vreg[par][j].w);
    }
  };

  auto COMPUTE = [&](const u16* Kc, const u16* Vc) {
    f32x4 sacc[2][4] = {};
    __builtin_amdgcn_s_setprio(1);
#pragma unroll
    for (int c = 0; c < 4; ++c) {
      int krow = c * 16 + r15;
      int sz = (krow & 7) << 4;
#pragma unroll
      for (int dh = 0; dh < 2; ++dh) {
        short8 kf = *(const short8*)((const char*)Kc + krow * 128 + ((dh * 64 + g * 16) ^ sz));
#pragma unroll
        for (int qi = 0; qi < 2; ++qi)
          sacc[qi][c] = __builtin_amdgcn_mfma_f32_16x16x32_bf16(kf, qf[qi][dh], sacc[qi][c], 0, 0, 0);
      }
    }
    __builtin_amdgcn_s_setprio(0);

    short8 pb[2][2];
#pragma unroll
    for (int qi = 0; qi < 2; ++qi) {
#pragma unroll
      for (int c = 0; c < 4; ++c)
#pragma unroll
        for (int r = 0; r < 4; ++r)
          sacc[qi][c][r] = vexp2(sacc[qi][c][r]);
#pragma unroll
      for (int kh = 0; kh < 2; ++kh) {
        union { uint32_t u[4]; short8 s; } pu;
        pu.u[0] = cvtpk(sacc[qi][2 * kh][0],     sacc[qi][2 * kh][1]);
        pu.u[1] = cvtpk(sacc[qi][2 * kh][2],     sacc[qi][2 * kh][3]);
        pu.u[2] = cvtpk(sacc[qi][2 * kh + 1][0], sacc[qi][2 * kh + 1][1]);
        pu.u[3] = cvtpk(sacc[qi][2 * kh + 1][2], sacc[qi][2 * kh + 1][3]);
        pb[qi][kh] = pu.s;
      }
    }
#pragma unroll
    for (int qi = 0; qi < 2; ++qi)
#pragma unroll
      for (int kh = 0; kh < 2; ++kh)
        ssum[qi] = __builtin_amdgcn_mfma_f32_16x16x32_bf16(kones, pb[qi][kh], ssum[qi], 0, 0, 0);

    __builtin_amdgcn_s_setprio(1);
#pragma unroll
    for (int dc = 0; dc < 4; ++dc) {
      int vrow = dc * 16 + r15;
      int sz = ((vrow & 7) << 4) | (((vrow >> 3) & 1) << 3);
      const char* vb = (const char*)Vc + vrow * 128;
#pragma unroll
      for (int kh = 0; kh < 2; ++kh) {
        union { uint2 v[2]; short8 s; } va;
        va.v[0] = *(const uint2*)(vb + ((kh * 64 + 8 * g) ^ sz));
        va.v[1] = *(const uint2*)(vb + ((kh * 64 + 32 + 8 * g) ^ sz));
#pragma unroll
        for (int qi = 0; qi < 2; ++qi)
          oacc[dc][qi] = __builtin_amdgcn_mfma_f32_16x16x32_bf16(va.s, pb[qi][kh], oacc[dc][qi], 0, 0, 0);
      }
    }
    __builtin_amdgcn_s_setprio(0);
  };

  auto STEP = [&](int tt, int kb, int vb, bool stv, bool ld) {
    if (stv) VSTORE((tt + 1) & 1, (tt + 1) & 1);
    if (ld) {
      VLOAD(tt & 1, (tt + 2) * 64);
      STAGE_K((tt + 2) % 3, (tt + 2) * 64);
    }
    COMPUTE(lsK[kb], lsV[vb]);
    if (tt < 31) {
      if (ld) asm volatile("s_waitcnt vmcnt(4)" ::: "memory");
      else    asm volatile("s_waitcnt vmcnt(0)" ::: "memory");
      asm volatile("s_waitcnt lgkmcnt(0)" ::: "memory");
      __builtin_amdgcn_s_barrier();
      __builtin_amdgcn_sched_barrier(0);
    }
  };

  VLOAD(0, 0);        STAGE_K(0, 0);
  VLOAD(1, 64);       STAGE_K(1, 64);
  VSTORE(0, 0);
  asm volatile("s_waitcnt vmcnt(4)" ::: "memory");
  asm volatile("s_waitcnt lgkmcnt(0)" ::: "memory");
  __builtin_amdgcn_s_barrier();
  __builtin_amdgcn_sched_barrier(0);

#pragma unroll 1
  for (int it = 0; it < 5; ++it) {
    int base = it * 6;
    STEP(base + 0, 0, 0, true, true);
    STEP(base + 1, 1, 1, true, true);
    STEP(base + 2, 2, 0, true, true);
    STEP(base + 3, 0, 1, true, true);
    STEP(base + 4, 1, 0, true, true);
    STEP(base + 5, 2, 1, true, true);
  }
  STEP(30, 0, 0, true, false);
  STEP(31, 1, 1, false, false);

  const int nb = bh >> 4, h = bh & 15;
  float inv[2] = { 1.0f / ssum[0][0], 1.0f / ssum[1][0] };
#pragma unroll
  for (int dc = 0; dc < 4; ++dc)
#pragma unroll
    for (int qi = 0; qi < 2; ++qi) {
      int q = q0 + w * 32 + qi * 16 + r15;
      int d = dc * 16 + g * 4;
      uint32_t a = cvtpk(oacc[dc][qi][0] * inv[qi], oacc[dc][qi][1] * inv[qi]);
      uint32_t b = cvtpk(oacc[dc][qi][2] * inv[qi], oacc[dc][qi][3] * inv[qi]);
      uint2* dst = (uint2*)&AO[((size_t)(nb * SEQ + q)) * EMBED + h * 64 + d];
      *dst = make_uint2(a, b);
    }
}

// ---------------- launch ----------------
extern "C" void kernel_launch(void* const* d_in, const int* in_sizes, int n_in,
                              void* d_out, int out_size, void* d_ws, size_t ws_size,
                              hipStream_t stream) {
  const float* values  = (const float*)d_in[0];
  const float* keys    = (const float*)d_in[1];
  const float* queries = (const float*)d_in[2];
  const float* W_v = (const float*)d_in[3];
  const float* W_k = (const float*)d_in[4];
  const float* W_q = (const float*)d_in[5];
  const float* W_o = (const float*)d_in[6];
  const float* b_o = (const float*)d_in[7];

  const size_t XSZ = (size_t)MROWS * EMBED;  // 8,388,608 elems
  const size_t WSZ = (size_t)EMBED * EMBED;  // 1,048,576 elems
  u16* ws = (u16*)d_ws;
  u16* Wvt = ws;
  u16* Wkt = Wvt + WSZ;
  u16* Wqt = Wkt + WSZ;
  u16* Wot = Wqt + WSZ;
  u16* Qb  = Wot + WSZ;
  u16* Kb  = Qb + XSZ;
  u16* Vtb = Kb + XSZ;
  u16* AO  = Vtb + XSZ;

  prep_kernel<<<4096, 256, 0, stream>>>(W_v, W_k, W_q, W_o, Wvt, Wkt, Wqt, Wot);

  // fold softmax scale (1/sqrt(1024)) and log2(e) into Q so attention uses exp2 directly
  const float QSCALE = 0.03125f * 1.4426950408889634f;
  qkv_gemm<<<1536, 256, 0, stream>>>(queries, keys, values, Wqt, Wkt, Wvt, Qb, Kb, Vtb, QSCALE);

  attn_kernel<<<1024, 256, 0, stream>>>(Qb, Kb, Vtb, AO);

  gemm_o<<<512, 256, 0, stream>>>(AO, Wot, (float*)d_out, b_o);
}

// Round 19
// 209.120 us; speedup vs baseline: 1.0761x; 1.0761x over previous
//
#include <hip/hip_runtime.h>
#include <hip/hip_bf16.h>
#include <stdint.h>

typedef __attribute__((ext_vector_type(8))) short short8;
typedef __attribute__((ext_vector_type(4))) float f32x4;
typedef unsigned short u16;

#define EMBED 1024
#define SEQ 2048
#define NBATCH 4
#define MROWS (NBATCH * SEQ) /* 8192 */

__device__ __forceinline__ u16 f2bf(float f) {
  union { float f; uint32_t u; } v; v.f = f;
  uint32_t r = v.u + 0x7fffu + ((v.u >> 16) & 1u);
  return (u16)(r >> 16);
}

__device__ __forceinline__ uint32_t cvtpk(float lo, float hi) {
  uint32_t r;
  asm("v_cvt_pk_bf16_f32 %0, %1, %2" : "=v"(r) : "v"(lo), "v"(hi));
  return r;
}

// raw HW 2^x
__device__ __forceinline__ float vexp2(float x) {
  float r;
  asm("v_exp_f32 %0, %1" : "=v"(r) : "v"(x));
  return r;
}

__device__ __forceinline__ void gld16(const void* g, void* l) {
  __builtin_amdgcn_global_load_lds((const __attribute__((address_space(1))) void*)g,
                                   (__attribute__((address_space(3))) void*)l, 16, 0, 0);
}

// ---------------- prep: 4 weight transposes fp32[k][n] -> bf16[n][k] ----------------
__global__ __launch_bounds__(256) void prep_kernel(const float* __restrict__ W0,
                                                   const float* __restrict__ W1,
                                                   const float* __restrict__ W2,
                                                   const float* __restrict__ W3,
                                                   u16* __restrict__ T0,
                                                   u16* __restrict__ T1,
                                                   u16* __restrict__ T2,
                                                   u16* __restrict__ T3) {
  int id = blockIdx.x;
  int z = id >> 10;
  const float* W = z == 0 ? W0 : (z == 1 ? W1 : (z == 2 ? W2 : W3));
  u16* Wt = z == 0 ? T0 : (z == 1 ? T1 : (z == 2 ? T2 : T3));
  __shared__ float tile[32][33];
  int bx = (id & 31) * 32, by = ((id >> 5) & 31) * 32;
  int tx = threadIdx.x & 31, ty = threadIdx.x >> 5; // 32 x 8
#pragma unroll
  for (int i = 0; i < 32; i += 8)
    tile[ty + i][tx] = W[(size_t)(by + ty + i) * EMBED + bx + tx];
  __syncthreads();
#pragma unroll
  for (int i = 0; i < 32; i += 8)
    Wt[(size_t)(bx + ty + i) * EMBED + by + tx] = f2bf(tile[tx][ty + i]);
}

// ---------------- QKV GEMM (R12-exact): fused fp32->bf16, BK=64, XCD co-location ----------------
__global__ __launch_bounds__(256) void qkv_gemm(const float* __restrict__ Aq,
                                                const float* __restrict__ Ak,
                                                const float* __restrict__ Av,
                                                const u16* __restrict__ Wqt,
                                                const u16* __restrict__ Wkt,
                                                const u16* __restrict__ Wvt,
                                                u16* __restrict__ Qb,
                                                u16* __restrict__ Kb,
                                                u16* __restrict__ Vtb,
                                                float qscale) {
  constexpr int K = 1024;
  __shared__ float lsAf[128 * 64];  // 32KB
  __shared__ u16 lsB[128 * 64];     // 16KB

  const int id = blockIdx.x;
  const int xcd = id & 7;
  const int rest = id >> 3;
  const int bx = rest & 7;
  const int p = (rest >> 3) * 8 + xcd;  // [0,192)
  const int z = p >> 6;
  const int by = p & 63;

  const float* A = z == 0 ? Aq : (z == 1 ? Ak : Av);
  const u16* Bt  = z == 0 ? Wqt : (z == 1 ? Wkt : Wvt);
  u16* outp      = z == 0 ? Qb : (z == 1 ? Kb : Vtb);
  const float oscale = z == 0 ? qscale : 1.0f;
  const int epi = (z == 2) ? 1 : 0;

  const int t = threadIdx.x, l = t & 63, w = t >> 6;
  const int g = l >> 4, r15 = l & 15;
  const int m0 = by * 128, n0 = bx * 128;
  const int wm = (w >> 1) * 64, wn = (w & 1) * 64;
  f32x4 acc[4][4] = {};

  const int srow = t >> 3;        // 0..31
  const int sc16 = (t & 7) * 16;  // byte chunk within 128B k-row
  const u16* Bp[4];
#pragma unroll
  for (int j = 0; j < 4; ++j) {
    int row = srow + j * 32;
    int colswz = (sc16 ^ ((row & 7) << 4)) >> 1;
    Bp[j] = Bt + (size_t)(n0 + row) * K + colswz;
  }

  const int arow_b = t >> 4;      // 0..15
  const int au = t & 15;          // dest 16B unit within 256B row
  const float* Apf[8];
#pragma unroll
  for (int j = 0; j < 8; ++j) {
    int row = j * 16 + arow_b;
    int s = ((row & 7) << 1) | ((row >> 3) & 1);
    Apf[j] = A + (size_t)(m0 + row) * K + (au ^ s) * 4;
  }

  for (int k0 = 0; k0 < K; k0 += 64) {
#pragma unroll
    for (int j = 0; j < 4; ++j)
      gld16(Bp[j] + k0, lsB + j * 2048 + w * 512);
#pragma unroll
    for (int j = 0; j < 8; ++j)
      gld16(Apf[j] + k0, (char*)lsAf + j * 4096 + w * 1024);
    __syncthreads();

    short8 af[2][4], bfv[2][4];
#pragma unroll
    for (int kk = 0; kk < 2; ++kk) {
#pragma unroll
      for (int mi = 0; mi < 4; ++mi) {
        int row = wm + mi * 16 + r15;
        int s = ((row & 7) << 1) | ((row >> 3) & 1);
        int v = kk * 8 + g * 2;
        const char* base = (const char*)lsAf + row * 256;
        f32x4 a0 = *(const f32x4*)(base + ((v ^ s) * 16));
        f32x4 a1 = *(const f32x4*)(base + (((v + 1) ^ s) * 16));
        union { uint32_t u[4]; short8 sv; } pu;
        pu.u[0] = cvtpk(a0[0], a0[1]);
        pu.u[1] = cvtpk(a0[2], a0[3]);
        pu.u[2] = cvtpk(a1[0], a1[1]);
        pu.u[3] = cvtpk(a1[2], a1[3]);
        af[kk][mi] = pu.sv;
      }
#pragma unroll
      for (int ni = 0; ni < 4; ++ni) {
        int row = wn + ni * 16 + r15;
        bfv[kk][ni] = *(const short8*)((const char*)lsB + row * 128 + ((kk * 64 + g * 16) ^ ((row & 7) << 4)));
      }
    }
#pragma unroll
    for (int kk = 0; kk < 2; ++kk)
#pragma unroll
      for (int mi = 0; mi < 4; ++mi)
#pragma unroll
        for (int ni = 0; ni < 4; ++ni)
          acc[mi][ni] = __builtin_amdgcn_mfma_f32_16x16x32_bf16(af[kk][mi], bfv[kk][ni], acc[mi][ni], 0, 0, 0);
    __syncthreads();
  }

#pragma unroll
  for (int mi = 0; mi < 4; ++mi)
#pragma unroll
    for (int ni = 0; ni < 4; ++ni)
#pragma unroll
      for (int r = 0; r < 4; ++r) {
        int row = m0 + wm + mi * 16 + g * 4 + r;   // D: row=(l>>4)*4+reg
        int col = n0 + wn + ni * 16 + r15;         //    col=l&15
        float v = acc[mi][ni][r];
        if (epi == 0) {
          ((u16*)outp)[(((size_t)(row >> 11) * 16 + (col >> 6)) * SEQ + (row & 2047)) * 64 + (col & 63)] = f2bf(v * oscale);
        } else {
          ((u16*)outp)[(((size_t)(row >> 11) * 16 + (col >> 6)) * 64 + (col & 63)) * SEQ + (row & 2047)] = f2bf(v);
        }
      }
}

// ---------------- final projection (R12-exact): C = A_bf16 * Wot^T, fp32 out + bias ----------------
__global__ __launch_bounds__(256) void gemm_o(const u16* __restrict__ A,
                                              const u16* __restrict__ Bt,
                                              float* __restrict__ outp,
                                              const float* __restrict__ bias) {
  constexpr int K = 1024;
  __shared__ u16 lsA[128 * 64];
  __shared__ u16 lsB[128 * 64];

  const int id = blockIdx.x;
  const int xcd = id & 7;
  const int rest = id >> 3;
  const int bx = rest & 7;
  const int by = (rest >> 3) * 8 + xcd;  // [0,64)

  const int t = threadIdx.x, l = t & 63, w = t >> 6;
  const int g = l >> 4, r15 = l & 15;
  const int m0 = by * 128, n0 = bx * 128;
  const int wm = (w >> 1) * 64, wn = (w & 1) * 64;
  f32x4 acc[4][4] = {};
  const int srow = t >> 3;
  const int sc16 = (t & 7) * 16;

  const u16* Ap[4]; const u16* Bp[4];
#pragma unroll
  for (int j = 0; j < 4; ++j) {
    int row = srow + j * 32;
    int colswz = (sc16 ^ ((row & 7) << 4)) >> 1;
    Ap[j] = A  + (size_t)(m0 + row) * K + colswz;
    Bp[j] = Bt + (size_t)(n0 + row) * K + colswz;
  }

  for (int k0 = 0; k0 < K; k0 += 64) {
#pragma unroll
    for (int j = 0; j < 4; ++j) {
      gld16(Ap[j] + k0, lsA + j * 2048 + w * 512);
      gld16(Bp[j] + k0, lsB + j * 2048 + w * 512);
    }
    __syncthreads();
    short8 af[2][4], bfv[2][4];
#pragma unroll
    for (int kk = 0; kk < 2; ++kk) {
#pragma unroll
      for (int mi = 0; mi < 4; ++mi) {
        int row = wm + mi * 16 + r15;
        af[kk][mi] = *(const short8*)((const char*)lsA + row * 128 + ((kk * 64 + g * 16) ^ ((row & 7) << 4)));
      }
#pragma unroll
      for (int ni = 0; ni < 4; ++ni) {
        int row = wn + ni * 16 + r15;
        bfv[kk][ni] = *(const short8*)((const char*)lsB + row * 128 + ((kk * 64 + g * 16) ^ ((row & 7) << 4)));
      }
    }
#pragma unroll
    for (int kk = 0; kk < 2; ++kk)
#pragma unroll
      for (int mi = 0; mi < 4; ++mi)
#pragma unroll
        for (int ni = 0; ni < 4; ++ni)
          acc[mi][ni] = __builtin_amdgcn_mfma_f32_16x16x32_bf16(af[kk][mi], bfv[kk][ni], acc[mi][ni], 0, 0, 0);
    __syncthreads();
  }

#pragma unroll
  for (int mi = 0; mi < 4; ++mi)
#pragma unroll
    for (int ni = 0; ni < 4; ++ni)
#pragma unroll
      for (int r = 0; r < 4; ++r) {
        int row = m0 + wm + mi * 16 + g * 4 + r;
        int col = n0 + wn + ni * 16 + r15;
        outp[(size_t)row * EMBED + col] = acc[mi][ni][r] + bias[col];
      }
}

// ---------------- flash attention: 3-deep counted-vmcnt pipeline ----------------
// R12 base; micro-tweaks: no post-barrier sched_barrier(0) (order-pinning hurts, m141);
// setprio(1) extended over the ssum MFMA pair.
__global__ __launch_bounds__(256) void attn_kernel(const u16* __restrict__ Q,
                                                   const u16* __restrict__ Kb,
                                                   const u16* __restrict__ Vt,
                                                   u16* __restrict__ AO) {
  __shared__ u16 lsK[3][64 * 64];
  __shared__ u16 lsV[2][64 * 64];
  const int t = threadIdx.x, l = t & 63, w = t >> 6;
  const int g = l >> 4, r15 = l & 15;

  const int flat = blockIdx.x;
  const int work = (flat & 7) * 128 + (flat >> 3);
  const int bh = work >> 4;
  const int q0 = (work & 15) * 128;

  const u16* Qh = Q + (size_t)bh * SEQ * 64;
  const u16* Kh = Kb + (size_t)bh * SEQ * 64;
  const u16* Vh = Vt + (size_t)bh * 64 * SEQ;

  short8 qf[2][2];
#pragma unroll
  for (int qi = 0; qi < 2; ++qi)
#pragma unroll
    for (int dh = 0; dh < 2; ++dh)
      qf[qi][dh] = *(const short8*)&Qh[(size_t)(q0 + w * 32 + qi * 16 + r15) * 64 + dh * 32 + g * 8];

  const short8 kones = { 0x3F80, 0x3F80, 0x3F80, 0x3F80, 0x3F80, 0x3F80, 0x3F80, 0x3F80 };
  f32x4 ssum[2] = {};
  f32x4 oacc[4][2] = {};

  const int srow = t >> 3;         // 0..31
  const int scolb = (t & 7) * 16;  // byte col within 128B row

  uint4 vreg[2][2];  // [tile parity][j]

  auto STAGE_K = [&](int buf, int kv0) {
#pragma unroll
    for (int j = 0; j < 2; ++j) {
      int row = j * 32 + srow;
      int colswz = (scolb ^ ((row & 7) << 4)) >> 1;
      gld16(Kh + (size_t)(kv0 + row) * 64 + colswz, &lsK[buf][j * 2048 + w * 512]);
    }
  };
  auto VLOAD = [&](int par, int kv0) {
#pragma unroll
    for (int j = 0; j < 2; ++j) {
      int row = j * 32 + srow;  // d-row of V^T
      vreg[par][j] = *(const uint4*)(Vh + (size_t)row * SEQ + kv0 + (scolb >> 1));
    }
  };
  auto VSTORE = [&](int buf, int par) {
#pragma unroll
    for (int j = 0; j < 2; ++j) {
      int row = j * 32 + srow;
      int c4 = (row & 7) << 4, c3 = ((row >> 3) & 1) << 3;
      char* base = (char*)&lsV[buf][0] + row * 128 + (scolb ^ c4);
      *(uint2*)(base + c3)       = make_uint2(vreg[par][j].x, vreg[par][j].y);
      *(uint2*)(base + (8 ^ c3)) = make_uint2(vreg[par][j].z, vreg[par][j].w);
    }
  };

  auto COMPUTE = [&](const u16* Kc, const u16* Vc) {
    f32x4 sacc[2][4] = {};
    __builtin_amdgcn_s_setprio(1);
#pragma unroll
    for (int c = 0; c < 4; ++c) {
      int krow = c * 16 + r15;
      int sz = (krow & 7) << 4;
#pragma unroll
      for (int dh = 0; dh < 2; ++dh) {
        short8 kf = *(const short8*)((const char*)Kc + krow * 128 + ((dh * 64 + g * 16) ^ sz));
#pragma unroll
        for (int qi = 0; qi < 2; ++qi)
          sacc[qi][c] = __builtin_amdgcn_mfma_f32_16x16x32_bf16(kf, qf[qi][dh], sacc[qi][c], 0, 0, 0);
      }
    }
    __builtin_amdgcn_s_setprio(0);

    short8 pb[2][2];
#pragma unroll
    for (int qi = 0; qi < 2; ++qi) {
#pragma unroll
      for (int c = 0; c < 4; ++c)
#pragma unroll
        for (int r = 0; r < 4; ++r)
          sacc[qi][c][r] = vexp2(sacc[qi][c][r]);
#pragma unroll
      for (int kh = 0; kh < 2; ++kh) {
        union { uint32_t u[4]; short8 s; } pu;
        pu.u[0] = cvtpk(sacc[qi][2 * kh][0],     sacc[qi][2 * kh][1]);
        pu.u[1] = cvtpk(sacc[qi][2 * kh][2],     sacc[qi][2 * kh][3]);
        pu.u[2] = cvtpk(sacc[qi][2 * kh + 1][0], sacc[qi][2 * kh + 1][1]);
        pu.u[3] = cvtpk(sacc[qi][2 * kh + 1][2], sacc[qi][2 * kh + 1][3]);
        pb[qi][kh] = pu.s;
      }
    }
    __builtin_amdgcn_s_setprio(1);
#pragma unroll
    for (int qi = 0; qi < 2; ++qi)
#pragma unroll
      for (int kh = 0; kh < 2; ++kh)
        ssum[qi] = __builtin_amdgcn_mfma_f32_16x16x32_bf16(kones, pb[qi][kh], ssum[qi], 0, 0, 0);

#pragma unroll
    for (int dc = 0; dc < 4; ++dc) {
      int vrow = dc * 16 + r15;
      int sz = ((vrow & 7) << 4) | (((vrow >> 3) & 1) << 3);
      const char* vb = (const char*)Vc + vrow * 128;
#pragma unroll
      for (int kh = 0; kh < 2; ++kh) {
        union { uint2 v[2]; short8 s; } va;
        va.v[0] = *(const uint2*)(vb + ((kh * 64 + 8 * g) ^ sz));
        va.v[1] = *(const uint2*)(vb + ((kh * 64 + 32 + 8 * g) ^ sz));
#pragma unroll
        for (int qi = 0; qi < 2; ++qi)
          oacc[dc][qi] = __builtin_amdgcn_mfma_f32_16x16x32_bf16(va.s, pb[qi][kh], oacc[dc][qi], 0, 0, 0);
      }
    }
    __builtin_amdgcn_s_setprio(0);
  };

  auto STEP = [&](int tt, int kb, int vb, bool stv, bool ld) {
    if (stv) VSTORE((tt + 1) & 1, (tt + 1) & 1);
    if (ld) {
      VLOAD(tt & 1, (tt + 2) * 64);
      STAGE_K((tt + 2) % 3, (tt + 2) * 64);
    }
    COMPUTE(lsK[kb], lsV[vb]);
    if (tt < 31) {
      if (ld) asm volatile("s_waitcnt vmcnt(4)" ::: "memory");
      else    asm volatile("s_waitcnt vmcnt(0)" ::: "memory");
      asm volatile("s_waitcnt lgkmcnt(0)" ::: "memory");
      __builtin_amdgcn_s_barrier();
    }
  };

  VLOAD(0, 0);        STAGE_K(0, 0);
  VLOAD(1, 64);       STAGE_K(1, 64);
  VSTORE(0, 0);
  asm volatile("s_waitcnt vmcnt(4)" ::: "memory");
  asm volatile("s_waitcnt lgkmcnt(0)" ::: "memory");
  __builtin_amdgcn_s_barrier();

#pragma unroll 1
  for (int it = 0; it < 5; ++it) {
    int base = it * 6;
    STEP(base + 0, 0, 0, true, true);
    STEP(base + 1, 1, 1, true, true);
    STEP(base + 2, 2, 0, true, true);
    STEP(base + 3, 0, 1, true, true);
    STEP(base + 4, 1, 0, true, true);
    STEP(base + 5, 2, 1, true, true);
  }
  STEP(30, 0, 0, true, false);
  STEP(31, 1, 1, false, false);

  const int nb = bh >> 4, h = bh & 15;
  float inv[2] = { 1.0f / ssum[0][0], 1.0f / ssum[1][0] };
#pragma unroll
  for (int dc = 0; dc < 4; ++dc)
#pragma unroll
    for (int qi = 0; qi < 2; ++qi) {
      int q = q0 + w * 32 + qi * 16 + r15;
      int d = dc * 16 + g * 4;
      uint32_t a = cvtpk(oacc[dc][qi][0] * inv[qi], oacc[dc][qi][1] * inv[qi]);
      uint32_t b = cvtpk(oacc[dc][qi][2] * inv[qi], oacc[dc][qi][3] * inv[qi]);
      uint2* dst = (uint2*)&AO[((size_t)(nb * SEQ + q)) * EMBED + h * 64 + d];
      *dst = make_uint2(a, b);
    }
}

// ---------------- launch ----------------
extern "C" void kernel_launch(void* const* d_in, const int* in_sizes, int n_in,
                              void* d_out, int out_size, void* d_ws, size_t ws_size,
                              hipStream_t stream) {
  const float* values  = (const float*)d_in[0];
  const float* keys    = (const float*)d_in[1];
  const float* queries = (const float*)d_in[2];
  const float* W_v = (const float*)d_in[3];
  const float* W_k = (const float*)d_in[4];
  const float* W_q = (const float*)d_in[5];
  const float* W_o = (const float*)d_in[6];
  const float* b_o = (const float*)d_in[7];

  const size_t XSZ = (size_t)MROWS * EMBED;  // 8,388,608 elems
  const size_t WSZ = (size_t)EMBED * EMBED;  // 1,048,576 elems
  u16* ws = (u16*)d_ws;
  u16* Wvt = ws;
  u16* Wkt = Wvt + WSZ;
  u16* Wqt = Wkt + WSZ;
  u16* Wot = Wqt + WSZ;
  u16* Qb  = Wot + WSZ;
  u16* Kb  = Qb + XSZ;
  u16* Vtb = Kb + XSZ;
  u16* AO  = Vtb + XSZ;

  prep_kernel<<<4096, 256, 0, stream>>>(W_v, W_k, W_q, W_o, Wvt, Wkt, Wqt, Wot);

  // fold softmax scale (1/sqrt(1024)) and log2(e) into Q so attention uses exp2 directly
  const float QSCALE = 0.03125f * 1.4426950408889634f;
  qkv_gemm<<<1536, 256, 0, stream>>>(queries, keys, values, Wqt, Wkt, Wvt, Qb, Kb, Vtb, QSCALE);

  attn_kernel<<<1024, 256, 0, stream>>>(Qb, Kb, Vtb, AO);

  gemm_o<<<512, 256, 0, stream>>>(AO, Wot, (float*)d_out, b_o);
}